// Round 16
// baseline (124.596 us; speedup 1.0000x reference)
//
#include <hip/hip_runtime.h>
#include <hip/hip_bf16.h>

// RandomProjectionQuantizer — 4-launch pipeline, block-local reductions (R16).
//  x:(16,2048,320) f32, mask:(16,2048) i32 (exactly 16384 ones),
//  W:(16,320) f32, codebook:(8192,16) f32 -> scalar int32 label
//
//  init    : zero slotctr (1 block).
//  project : R14-verbatim (LDS-W, coalesced x, per-block slot atomicAdd).
//  phase1  : block = strip (512 blocks); wave covers 4 segs; rowmin plain
//            store — no global atomicMin, no 0xFF init.
//  tail    : 1 block x 1024 — gate + cproj (LDS-W) + rescore + rank emit,
//            all in-block (no key/ticket/global argmin).

#define NMASK   16384
#define NROWS   32768
#define D       320
#define CDIM    16
#define NCODES  8192
#define EPS_C   0.0117f      // 1.5 * 2^-7  (bf16 RNE dot-error coefficient)
#define EPS_ABS 0.02f

typedef __attribute__((ext_vector_type(8))) short short8;
typedef __attribute__((ext_vector_type(4))) float f32x4;

__device__ inline unsigned int encf(float f) {
  unsigned int u = __float_as_uint(f);
  return (u & 0x80000000u) ? ~u : (u | 0x80000000u);
}
__device__ inline float decf(unsigned int u) {
  unsigned int b = (u & 0x80000000u) ? (u & 0x7fffffffu) : ~u;
  return __uint_as_float(b);
}
__device__ inline unsigned short f2bf(float f) {   // RNE f32->bf16
  unsigned int u = __float_as_uint(f);
  unsigned int r = u + 0x7fffu + ((u >> 16) & 1u);
  return (unsigned short)(r >> 16);
}
__device__ inline float bf2f(unsigned short h) {
  return __uint_as_float(((unsigned int)h) << 16);
}

// LDS-W projection body (R12/R14-proven): lane ch covers d in {j*32+ch*4..+4},
// x prefetched (10-deep MLP), butterfly combine (xor 1,2,4).
__device__ inline void proj_lds(const float* __restrict__ x,
                                const float* __restrict__ Wl,
                                int row, int ch, float pd[16]) {
  const float* xr = x + (size_t)row * D + ch * 4;
  float4 xv[10];
#pragma unroll
  for (int j = 0; j < 10; ++j) xv[j] = *(const float4*)(xr + j * 32);
#pragma unroll
  for (int c = 0; c < 16; ++c) pd[c] = 0.f;
#pragma unroll
  for (int j = 0; j < 10; ++j) {
#pragma unroll
    for (int c = 0; c < 16; ++c) {
      const float4 wv = *(const float4*)&Wl[c * D + j * 32 + ch * 4];
      float acc = fmaf(xv[j].x, wv.x, pd[c]);
      acc = fmaf(xv[j].y, wv.y, acc);
      acc = fmaf(xv[j].z, wv.z, acc);
      pd[c] = fmaf(xv[j].w, wv.w, acc);
    }
  }
#pragma unroll
  for (int c = 0; c < 16; ++c) {
    pd[c] += __shfl_xor(pd[c], 1);
    pd[c] += __shfl_xor(pd[c], 2);
    pd[c] += __shfl_xor(pd[c], 4);
  }
}

// ---------------- Kernel 0: init (1 block x 64) ------------------------------
__global__ void init_kernel(unsigned int* __restrict__ ctrs) {
  if (threadIdx.x < 4) ctrs[threadIdx.x] = 0u;      // slotctr (+spare)
}

// ---------------- Kernel 1: project (1024 blocks x 256, R14-verbatim) --------
__global__ __launch_bounds__(256) void project_kernel(
    const float* __restrict__ x, const int* __restrict__ mask,
    const float* __restrict__ W, const float* __restrict__ cbk,
    float* __restrict__ c2, unsigned short* __restrict__ cbf32,
    unsigned short* __restrict__ tbf32, float* __restrict__ t2arr,
    int* __restrict__ origrow, unsigned int* __restrict__ slotctr) {
  __shared__ float Wl[CDIM * D];                    // 20 KiB, natural layout
  __shared__ unsigned long long mb;
  __shared__ unsigned int wcnt[4], wbase[4];
  int tid = threadIdx.x, bid = (int)blockIdx.x;
  int chunk = bid >> 1, half = bid & 1;
  for (int i = tid; i < (CDIM * D) / 4; i += 256)
    ((float4*)Wl)[i] = ((const float4*)W)[i];
  if (tid < 64) {
    int m = mask[chunk * 64 + tid];
    unsigned long long bal = __ballot(m != 0);
    if (tid == 0) mb = bal;
  }
  __syncthreads();

  if (bid < 512 && tid < 16) {                      // fused codes job (R5 fold)
    int k = bid * 16 + tid;
    const float4* p = (const float4*)(cbk + (long)k * CDIM);
    float s = 0.f; unsigned short nb[16];
#pragma unroll
    for (int q = 0; q < 4; ++q) {
      float4 v = p[q];
      s = fmaf(v.x, v.x, s); s = fmaf(v.y, v.y, s);
      s = fmaf(v.z, v.z, s); s = fmaf(v.w, v.w, s);
      nb[q*4+0] = f2bf(-2.0f * v.x); nb[q*4+1] = f2bf(-2.0f * v.y);
      nb[q*4+2] = f2bf(-2.0f * v.z); nb[q*4+3] = f2bf(-2.0f * v.w);
    }
    c2[k] = s;
    unsigned short g1 = f2bf(s);
    unsigned short g2 = f2bf(s - bf2f(g1));
    uint4 pk0, pk1, pk2, pk3;
    pk0.x = (unsigned int)nb[0]  | ((unsigned int)nb[1]  << 16);
    pk0.y = (unsigned int)nb[2]  | ((unsigned int)nb[3]  << 16);
    pk0.z = (unsigned int)nb[4]  | ((unsigned int)nb[5]  << 16);
    pk0.w = (unsigned int)nb[6]  | ((unsigned int)nb[7]  << 16);
    pk1.x = (unsigned int)nb[8]  | ((unsigned int)nb[9]  << 16);
    pk1.y = (unsigned int)nb[10] | ((unsigned int)nb[11] << 16);
    pk1.z = (unsigned int)nb[12] | ((unsigned int)nb[13] << 16);
    pk1.w = (unsigned int)nb[14] | ((unsigned int)nb[15] << 16);
    pk2.x = (unsigned int)g1 | ((unsigned int)g2 << 16); // dims 16,17: g1,g2
    pk2.y = 0x3F803F80u;                                 // dims 18,19: 1,1
    pk2.z = 0u; pk2.w = 0u;
    pk3.x = 0u; pk3.y = 0u; pk3.z = 0u; pk3.w = 0u;
    uint4* dst = (uint4*)(cbf32 + (long)k * 32);
    dst[0] = pk0; dst[1] = pk1; dst[2] = pk2; dst[3] = pk3;
  }

  unsigned long long B0 = mb;
  int r = tid >> 3, ch = tid & 7, lane = tid & 63, w = tid >> 6;
  int p = half * 32 + r;                            // bit position in chunk
  int row = chunk * 64 + p;
  int m = (int)((B0 >> p) & 1ull);

  // per-BLOCK slot assignment: one atomicAdd per block (R13-proven)
  unsigned long long wbal = __ballot(m && ch == 0);
  if (lane == 0) wcnt[w] = (unsigned int)__popcll(wbal);
  __syncthreads();
  if (tid == 0) {
    unsigned int tot = wcnt[0] + wcnt[1] + wcnt[2] + wcnt[3];
    unsigned int b = tot ? atomicAdd(slotctr, tot) : 0u;
    wbase[0] = b;
    wbase[1] = b + wcnt[0];
    wbase[2] = b + wcnt[0] + wcnt[1];
    wbase[3] = b + wcnt[0] + wcnt[1] + wcnt[2];
  }
  __syncthreads();
  if (!m) return;                                   // no barriers past here

  float pd[16];
  proj_lds(x, Wl, row, ch, pd);                     // R12-proven body

  if (ch == 0) {
    int slot = (int)wbase[w] + __popcll(wbal & ((1ull << lane) - 1ull));
    float t2 = 0.f;
#pragma unroll
    for (int c = 0; c < 16; ++c) t2 = fmaf(pd[c], pd[c], t2);
    t2arr[slot] = t2;
    origrow[slot] = row;
    unsigned short tb[16];
#pragma unroll
    for (int c = 0; c < 16; ++c) tb[c] = f2bf(pd[c]);
    unsigned short h1 = f2bf(t2);
    unsigned short h2 = f2bf(t2 - bf2f(h1));
    uint4 pk0, pk1, pk2, pk3;
    pk0.x = (unsigned int)tb[0]  | ((unsigned int)tb[1]  << 16);
    pk0.y = (unsigned int)tb[2]  | ((unsigned int)tb[3]  << 16);
    pk0.z = (unsigned int)tb[4]  | ((unsigned int)tb[5]  << 16);
    pk0.w = (unsigned int)tb[6]  | ((unsigned int)tb[7]  << 16);
    pk1.x = (unsigned int)tb[8]  | ((unsigned int)tb[9]  << 16);
    pk1.y = (unsigned int)tb[10] | ((unsigned int)tb[11] << 16);
    pk1.z = (unsigned int)tb[12] | ((unsigned int)tb[13] << 16);
    pk1.w = (unsigned int)tb[14] | ((unsigned int)tb[15] << 16);
    pk2.x = 0x3F803F80u;                                 // dims 16,17: 1,1
    pk2.y = (unsigned int)h1 | ((unsigned int)h2 << 16); // dims 18,19: h1,h2
    pk2.z = 0u; pk2.w = 0u;
    pk3.x = 0u; pk3.y = 0u; pk3.z = 0u; pk3.w = 0u;
    uint4* dst = (uint4*)(tbf32 + (long)slot * 32);
    dst[0] = pk0; dst[1] = pk1; dst[2] = pk2; dst[3] = pk3;
  }
}

// ---------------- Kernel 2: MFMA screening, block = strip (512 x 256) --------
// Wave w covers segs {s4*4+w}; per-strip minima complete in-block -> plain
// store to rowmin_u (no global atomics, no init).
__global__ __launch_bounds__(256) void phase1_kernel(
    const unsigned short* __restrict__ tbf32,
    const unsigned short* __restrict__ cbf32,
    unsigned int* __restrict__ rowmin_u) {
  __shared__ unsigned int rml[4 * 33];
  int tid = threadIdx.x;
  int w = tid >> 6, l = tid & 63, lr = l & 15, g = l >> 4;
  int row0 = (int)blockIdx.x * 32;

  for (int i = tid; i < 4 * 33; i += 256) rml[i] = 0xFFFFFFFFu;

  const f32x4 zero = {0.f, 0.f, 0.f, 0.f};
  short8 calA = {0,0,0,0,0,0,0,0}, calB = {0,0,0,0,0,0,0,0};
  if (g == 0) {
    calA[0] = (short)f2bf((float)(lr + 1));
    calB[0] = (short)0x3F80;                        // bf16 1.0
  }
  f32x4 cal = __builtin_amdgcn_mfma_f32_16x16x32_bf16(calA, calB, zero, 0, 0, 0);
  int rid[4];
#pragma unroll
  for (int j = 0; j < 4; ++j) {
    int v = (int)(cal[j] + 0.5f) - 1;
    rid[j] = v < 0 ? 0 : (v > 15 ? 15 : v);
  }

  const short8 a0 = *(const short8*)(tbf32 + (long)(row0 + lr) * 32 + g * 8);
  const short8 a1 = *(const short8*)(tbf32 + (long)(row0 + 16 + lr) * 32 + g * 8);
  f32x4 rmin0 = {3.4e38f, 3.4e38f, 3.4e38f, 3.4e38f};
  f32x4 rmin1 = rmin0;
#pragma unroll
  for (int s4 = 0; s4 < 4; ++s4) {                  // wave w: segs s4*4+w
    int code0 = (s4 * 4 + w) * 512;
#pragma unroll 2
    for (int t = 0; t < 32; ++t) {
      int code = code0 + t * 16 + lr;
      short8 b = *(const short8*)(cbf32 + (long)code * 32 + g * 8);
      f32x4 d0 = __builtin_amdgcn_mfma_f32_16x16x32_bf16(a0, b, zero, 0, 0, 0);
      f32x4 d1 = __builtin_amdgcn_mfma_f32_16x16x32_bf16(a1, b, zero, 0, 0, 0);
#pragma unroll
      for (int j = 0; j < 4; ++j) {
        rmin0[j] = fminf(rmin0[j], d0[j]);
        rmin1[j] = fminf(rmin1[j], d1[j]);
      }
    }
  }
  __syncthreads();                                  // rml init visible
  unsigned int* mywave = &rml[w * 33];
#pragma unroll
  for (int j = 0; j < 4; ++j) {
    atomicMin(&mywave[rid[j]],      encf(rmin0[j]));
    atomicMin(&mywave[16 + rid[j]], encf(rmin1[j]));
  }
  __syncthreads();
  if (tid < 32) {                                   // plain store (block-local)
    unsigned int mn = 0xFFFFFFFFu;
#pragma unroll
    for (int ww = 0; ww < 4; ++ww) mn = min(mn, rml[ww * 33 + tid]);
    rowmin_u[row0 + tid] = mn;
  }
}

// ---------------- Kernel 3: tail — gate + cproj + rescore + emit (1 x 1024) --
__global__ __launch_bounds__(1024) void tail_kernel(
    const float* __restrict__ x, const float* __restrict__ W,
    const float* __restrict__ cbk, const float* __restrict__ c2,
    const float* __restrict__ t2arr, const int* __restrict__ origrow,
    const unsigned int* __restrict__ rowmin_u, const int* __restrict__ mask,
    int* __restrict__ candlist, float* __restrict__ tgtm,
    int* __restrict__ out) {
  __shared__ float Wl[CDIM * D];                    // 20 KiB
  __shared__ float red_f[1024];
  __shared__ unsigned long long red_u[1024];        // 8 KiB
  __shared__ unsigned int cnt_s;
  __shared__ unsigned int vlow_s;
  int tid = threadIdx.x;

  for (int i = tid; i < (CDIM * D) / 4; i += 1024)
    ((float4*)Wl)[i] = ((const float4*)W)[i];
  // --- gate: c2max ---
  float cm = 0.f;
  for (int i = tid; i < NCODES; i += 1024) cm = fmaxf(cm, c2[i]);
  red_f[tid] = cm;
  if (tid == 0) cnt_s = 0u;
  __syncthreads();
  for (int s = 512; s > 0; s >>= 1) {
    if (tid < s) red_f[tid] = fmaxf(red_f[tid], red_f[tid + s]);
    __syncthreads();
  }
  float c2m = red_f[0];
  __syncthreads();
  // --- gate: T = min_r (a_r + eps_r) ---
  float Tl = 3.4e38f;
  for (int i = tid; i < NMASK; i += 1024) {
    float a = decf(rowmin_u[i]);
    float e = fmaf(EPS_C, sqrtf(t2arr[i] * c2m), EPS_ABS);
    Tl = fminf(Tl, a + e);                          // NaN -> ignored
  }
  red_f[tid] = Tl;
  __syncthreads();
  for (int s = 512; s > 0; s >>= 1) {
    if (tid < s) red_f[tid] = fminf(red_f[tid], red_f[tid + s]);
    __syncthreads();
  }
  float T = red_f[0];
  // --- gate: candidates ---
  for (int i = tid; i < NMASK; i += 1024) {
    float a = decf(rowmin_u[i]);
    float e = fmaf(EPS_C, sqrtf(t2arr[i] * c2m), EPS_ABS);
    if (!(a - e > T)) {                             // NaN-safe: NaN -> candidate
      unsigned int pos = atomicAdd(&cnt_s, 1u);
      candlist[pos] = i;
    }
  }
  __syncthreads();
  int nc = (int)cnt_s;
  // --- cproj: 128 groups of 8 lanes, bit-identical chain ---
  int grp = tid >> 3, ch = tid & 7;
  for (int idx = grp; idx < nc; idx += 128) {
    int row = origrow[candlist[idx]];
    float pd[16];
    proj_lds(x, Wl, row, ch, pd);
    if (ch == 0) {
      float* op = tgtm + (long)idx * 16;
#pragma unroll
      for (int c = 0; c < 16; ++c) op[c] = -2.0f * pd[c];
    }
  }
  __syncthreads();
  // --- rescore: global u64 min over (dist, row*8192+code) ---
  unsigned long long best = 0xFFFFFFFFFFFFFFFFull;
  for (int ci = 0; ci < nc; ++ci) {
    int slot = candlist[ci];
    float t2 = t2arr[slot];
    int row = origrow[slot];
    float tm[16];
    const float4* tp = (const float4*)(tgtm + (long)ci * 16);
#pragma unroll
    for (int q = 0; q < 4; ++q) {                   // uniform -> scalar loads
      float4 v = tp[q];
      tm[q*4+0] = v.x; tm[q*4+1] = v.y; tm[q*4+2] = v.z; tm[q*4+3] = v.w;
    }
#pragma unroll 2
    for (int k = 0; k < 8; ++k) {                   // 8 codes/thread
      int code = k * 1024 + tid;
      const float4* cp = (const float4*)(cbk + (long)code * CDIM);
      float4 c0 = cp[0], c1 = cp[1], c2v4 = cp[2], c3 = cp[3];
      float acc = fmaf(tm[0],  c0.x, c2[code]);
      acc = fmaf(tm[1],  c0.y, acc);   acc = fmaf(tm[2],  c0.z, acc);
      acc = fmaf(tm[3],  c0.w, acc);   acc = fmaf(tm[4],  c1.x, acc);
      acc = fmaf(tm[5],  c1.y, acc);   acc = fmaf(tm[6],  c1.z, acc);
      acc = fmaf(tm[7],  c1.w, acc);   acc = fmaf(tm[8],  c2v4.x, acc);
      acc = fmaf(tm[9],  c2v4.y, acc); acc = fmaf(tm[10], c2v4.z, acc);
      acc = fmaf(tm[11], c2v4.w, acc); acc = fmaf(tm[12], c3.x, acc);
      acc = fmaf(tm[13], c3.y, acc);   acc = fmaf(tm[14], c3.z, acc);
      acc = fmaf(tm[15], c3.w, acc);
      unsigned long long pk = ((unsigned long long)encf(t2 + acc) << 32)
          | (unsigned long long)((unsigned int)row * (unsigned int)NCODES
                                 + (unsigned int)code);
      best = (pk < best) ? pk : best;               // (row,code) lex tie-break
    }
  }
  red_u[tid] = best;
  __syncthreads();
  for (int s = 512; s > 0; s >>= 1) {
    if (tid < s) { if (red_u[tid + s] < red_u[tid]) red_u[tid] = red_u[tid + s]; }
    __syncthreads();
  }
  // --- emit: winner row -> rank via mask popcount ---
  if (tid == 0) vlow_s = (unsigned int)(red_u[0] & 0xFFFFFFFFull);
  __syncthreads();
  unsigned int vlow = vlow_s;
  int wrow = (int)(vlow >> 13), wcode = (int)(vlow & 8191u);
  int lo = tid * (NROWS / 1024);
  int hi = lo + (NROWS / 1024); if (hi > wrow) hi = wrow;
  int cnt = 0;
#pragma unroll 4
  for (int i = lo; i < hi; ++i) cnt += (mask[i] != 0);
  red_u[tid] = (unsigned long long)cnt;
  __syncthreads();
  for (int s = 512; s > 0; s >>= 1) {
    if (tid < s) red_u[tid] += red_u[tid + s];
    __syncthreads();
  }
  if (tid == 0) out[0] = (int)red_u[0] * NCODES + wcode;  // rank*8192 + code
}

extern "C" void kernel_launch(void* const* d_in, const int* in_sizes, int n_in,
                              void* d_out, int out_size, void* d_ws, size_t ws_size,
                              hipStream_t stream) {
  const float* x    = (const float*)d_in[0];
  const int*   mask = (const int*)d_in[1];
  const float* W    = (const float*)d_in[2];
  const float* cbk  = (const float*)d_in[3];
  int* out = (int*)d_out;

  char* ws = (char*)d_ws;                                   // total 1,810,432 B (R6-proven)
  unsigned int*       ctrs      = (unsigned int*)(ws + 4096);       // slotctr (+spare)
  unsigned int*       slotctr   = (unsigned int*)(ws + 4096);
  unsigned int*       rowmin_u  = (unsigned int*)(ws + 8192);       // 64 KiB
  float*              t2arr     = (float*)(ws + 73728);             // 64 KiB
  int*                origrow   = (int*)(ws + 139264);              // 64 KiB
  float*              c2        = (float*)(ws + 204800);            // 32 KiB
  unsigned short*     cbf32     = (unsigned short*)(ws + 237568);   // 512 KiB
  int*                candlist  = (int*)(ws + 237568);              // aliases cbf32 (dead by tail)
  unsigned short*     tbf32     = (unsigned short*)(ws + 761856);   // 1 MiB
  float*              tgtm      = (float*)(ws + 761856);            // aliases tbf32 (dead after phase1)

  init_kernel<<<1, 64, 0, stream>>>(ctrs);
  project_kernel<<<1024, 256, 0, stream>>>(x, mask, W, cbk, c2, cbf32, tbf32,
                                           t2arr, origrow, slotctr);
  phase1_kernel<<<512, 256, 0, stream>>>(tbf32, cbf32, rowmin_u);
  tail_kernel<<<1, 1024, 0, stream>>>(x, W, cbk, c2, t2arr, origrow, rowmin_u,
                                      mask, candlist, tgtm, out);
}

// Round 17
// 115.721 us; speedup vs baseline: 1.0767x; 1.0767x over previous
//
#include <hip/hip_runtime.h>
#include <hip/hip_bf16.h>

// RandomProjectionQuantizer — R17: R16 minus the serial-rescore mistake.
//  x:(16,2048,320) f32, mask:(16,2048) i32 (exactly 16384 ones),
//  W:(16,320) f32, codebook:(8192,16) f32 -> scalar int32 label
//
//  init    : zero slotctr/resctr, key=FF (1 block).
//  project : R14-verbatim (LDS-W, coalesced x, per-block slot atomicAdd).
//  phase1  : R16-verbatim (block=strip, rowmin plain store).
//  gatecp  : 1 block x 1024 — gate + cproj fused (nc ~ O(100) candidates).
//  rescore : R14-verbatim multi-block (512) over (cand, octant) units,
//            u64 atomicMin + ticket + rank-converting emit.

#define NMASK   16384
#define NROWS   32768
#define D       320
#define CDIM    16
#define NCODES  8192
#define EPS_C   0.0117f      // 1.5 * 2^-7  (bf16 RNE dot-error coefficient)
#define EPS_ABS 0.02f

typedef __attribute__((ext_vector_type(8))) short short8;
typedef __attribute__((ext_vector_type(4))) float f32x4;

__device__ inline unsigned int encf(float f) {
  unsigned int u = __float_as_uint(f);
  return (u & 0x80000000u) ? ~u : (u | 0x80000000u);
}
__device__ inline float decf(unsigned int u) {
  unsigned int b = (u & 0x80000000u) ? (u & 0x7fffffffu) : ~u;
  return __uint_as_float(b);
}
__device__ inline unsigned short f2bf(float f) {   // RNE f32->bf16
  unsigned int u = __float_as_uint(f);
  unsigned int r = u + 0x7fffu + ((u >> 16) & 1u);
  return (unsigned short)(r >> 16);
}
__device__ inline float bf2f(unsigned short h) {
  return __uint_as_float(((unsigned int)h) << 16);
}

// LDS-W projection body (R12/R14-proven): lane ch covers d in {j*32+ch*4..+4},
// x prefetched (10-deep MLP), butterfly combine (xor 1,2,4).
__device__ inline void proj_lds(const float* __restrict__ x,
                                const float* __restrict__ Wl,
                                int row, int ch, float pd[16]) {
  const float* xr = x + (size_t)row * D + ch * 4;
  float4 xv[10];
#pragma unroll
  for (int j = 0; j < 10; ++j) xv[j] = *(const float4*)(xr + j * 32);
#pragma unroll
  for (int c = 0; c < 16; ++c) pd[c] = 0.f;
#pragma unroll
  for (int j = 0; j < 10; ++j) {
#pragma unroll
    for (int c = 0; c < 16; ++c) {
      const float4 wv = *(const float4*)&Wl[c * D + j * 32 + ch * 4];
      float acc = fmaf(xv[j].x, wv.x, pd[c]);
      acc = fmaf(xv[j].y, wv.y, acc);
      acc = fmaf(xv[j].z, wv.z, acc);
      pd[c] = fmaf(xv[j].w, wv.w, acc);
    }
  }
#pragma unroll
  for (int c = 0; c < 16; ++c) {
    pd[c] += __shfl_xor(pd[c], 1);
    pd[c] += __shfl_xor(pd[c], 2);
    pd[c] += __shfl_xor(pd[c], 4);
  }
}

// ---------------- Kernel 0: init (1 block x 64) ------------------------------
__global__ void init_kernel(unsigned int* __restrict__ ctrs,
                            unsigned long long* __restrict__ key) {
  if (threadIdx.x < 4) ctrs[threadIdx.x] = 0u;      // slotctr, resctr (+spare)
  if (threadIdx.x == 4) key[0] = 0xFFFFFFFFFFFFFFFFull;
}

// ---------------- Kernel 1: project (1024 blocks x 256, R14-verbatim) --------
__global__ __launch_bounds__(256) void project_kernel(
    const float* __restrict__ x, const int* __restrict__ mask,
    const float* __restrict__ W, const float* __restrict__ cbk,
    float* __restrict__ c2, unsigned short* __restrict__ cbf32,
    unsigned short* __restrict__ tbf32, float* __restrict__ t2arr,
    int* __restrict__ origrow, unsigned int* __restrict__ slotctr) {
  __shared__ float Wl[CDIM * D];                    // 20 KiB, natural layout
  __shared__ unsigned long long mb;
  __shared__ unsigned int wcnt[4], wbase[4];
  int tid = threadIdx.x, bid = (int)blockIdx.x;
  int chunk = bid >> 1, half = bid & 1;
  for (int i = tid; i < (CDIM * D) / 4; i += 256)
    ((float4*)Wl)[i] = ((const float4*)W)[i];
  if (tid < 64) {
    int m = mask[chunk * 64 + tid];
    unsigned long long bal = __ballot(m != 0);
    if (tid == 0) mb = bal;
  }
  __syncthreads();

  if (bid < 512 && tid < 16) {                      // fused codes job (R5 fold)
    int k = bid * 16 + tid;
    const float4* p = (const float4*)(cbk + (long)k * CDIM);
    float s = 0.f; unsigned short nb[16];
#pragma unroll
    for (int q = 0; q < 4; ++q) {
      float4 v = p[q];
      s = fmaf(v.x, v.x, s); s = fmaf(v.y, v.y, s);
      s = fmaf(v.z, v.z, s); s = fmaf(v.w, v.w, s);
      nb[q*4+0] = f2bf(-2.0f * v.x); nb[q*4+1] = f2bf(-2.0f * v.y);
      nb[q*4+2] = f2bf(-2.0f * v.z); nb[q*4+3] = f2bf(-2.0f * v.w);
    }
    c2[k] = s;
    unsigned short g1 = f2bf(s);
    unsigned short g2 = f2bf(s - bf2f(g1));
    uint4 pk0, pk1, pk2, pk3;
    pk0.x = (unsigned int)nb[0]  | ((unsigned int)nb[1]  << 16);
    pk0.y = (unsigned int)nb[2]  | ((unsigned int)nb[3]  << 16);
    pk0.z = (unsigned int)nb[4]  | ((unsigned int)nb[5]  << 16);
    pk0.w = (unsigned int)nb[6]  | ((unsigned int)nb[7]  << 16);
    pk1.x = (unsigned int)nb[8]  | ((unsigned int)nb[9]  << 16);
    pk1.y = (unsigned int)nb[10] | ((unsigned int)nb[11] << 16);
    pk1.z = (unsigned int)nb[12] | ((unsigned int)nb[13] << 16);
    pk1.w = (unsigned int)nb[14] | ((unsigned int)nb[15] << 16);
    pk2.x = (unsigned int)g1 | ((unsigned int)g2 << 16); // dims 16,17: g1,g2
    pk2.y = 0x3F803F80u;                                 // dims 18,19: 1,1
    pk2.z = 0u; pk2.w = 0u;
    pk3.x = 0u; pk3.y = 0u; pk3.z = 0u; pk3.w = 0u;
    uint4* dst = (uint4*)(cbf32 + (long)k * 32);
    dst[0] = pk0; dst[1] = pk1; dst[2] = pk2; dst[3] = pk3;
  }

  unsigned long long B0 = mb;
  int r = tid >> 3, ch = tid & 7, lane = tid & 63, w = tid >> 6;
  int p = half * 32 + r;                            // bit position in chunk
  int row = chunk * 64 + p;
  int m = (int)((B0 >> p) & 1ull);

  // per-BLOCK slot assignment: one atomicAdd per block (R13-proven)
  unsigned long long wbal = __ballot(m && ch == 0);
  if (lane == 0) wcnt[w] = (unsigned int)__popcll(wbal);
  __syncthreads();
  if (tid == 0) {
    unsigned int tot = wcnt[0] + wcnt[1] + wcnt[2] + wcnt[3];
    unsigned int b = tot ? atomicAdd(slotctr, tot) : 0u;
    wbase[0] = b;
    wbase[1] = b + wcnt[0];
    wbase[2] = b + wcnt[0] + wcnt[1];
    wbase[3] = b + wcnt[0] + wcnt[1] + wcnt[2];
  }
  __syncthreads();
  if (!m) return;                                   // no barriers past here

  float pd[16];
  proj_lds(x, Wl, row, ch, pd);                     // R12-proven body

  if (ch == 0) {
    int slot = (int)wbase[w] + __popcll(wbal & ((1ull << lane) - 1ull));
    float t2 = 0.f;
#pragma unroll
    for (int c = 0; c < 16; ++c) t2 = fmaf(pd[c], pd[c], t2);
    t2arr[slot] = t2;
    origrow[slot] = row;
    unsigned short tb[16];
#pragma unroll
    for (int c = 0; c < 16; ++c) tb[c] = f2bf(pd[c]);
    unsigned short h1 = f2bf(t2);
    unsigned short h2 = f2bf(t2 - bf2f(h1));
    uint4 pk0, pk1, pk2, pk3;
    pk0.x = (unsigned int)tb[0]  | ((unsigned int)tb[1]  << 16);
    pk0.y = (unsigned int)tb[2]  | ((unsigned int)tb[3]  << 16);
    pk0.z = (unsigned int)tb[4]  | ((unsigned int)tb[5]  << 16);
    pk0.w = (unsigned int)tb[6]  | ((unsigned int)tb[7]  << 16);
    pk1.x = (unsigned int)tb[8]  | ((unsigned int)tb[9]  << 16);
    pk1.y = (unsigned int)tb[10] | ((unsigned int)tb[11] << 16);
    pk1.z = (unsigned int)tb[12] | ((unsigned int)tb[13] << 16);
    pk1.w = (unsigned int)tb[14] | ((unsigned int)tb[15] << 16);
    pk2.x = 0x3F803F80u;                                 // dims 16,17: 1,1
    pk2.y = (unsigned int)h1 | ((unsigned int)h2 << 16); // dims 18,19: h1,h2
    pk2.z = 0u; pk2.w = 0u;
    pk3.x = 0u; pk3.y = 0u; pk3.z = 0u; pk3.w = 0u;
    uint4* dst = (uint4*)(tbf32 + (long)slot * 32);
    dst[0] = pk0; dst[1] = pk1; dst[2] = pk2; dst[3] = pk3;
  }
}

// ---------------- Kernel 2: MFMA screening (512 x 256, R16-verbatim) ---------
__global__ __launch_bounds__(256) void phase1_kernel(
    const unsigned short* __restrict__ tbf32,
    const unsigned short* __restrict__ cbf32,
    unsigned int* __restrict__ rowmin_u) {
  __shared__ unsigned int rml[4 * 33];
  int tid = threadIdx.x;
  int w = tid >> 6, l = tid & 63, lr = l & 15, g = l >> 4;
  int row0 = (int)blockIdx.x * 32;

  for (int i = tid; i < 4 * 33; i += 256) rml[i] = 0xFFFFFFFFu;

  const f32x4 zero = {0.f, 0.f, 0.f, 0.f};
  short8 calA = {0,0,0,0,0,0,0,0}, calB = {0,0,0,0,0,0,0,0};
  if (g == 0) {
    calA[0] = (short)f2bf((float)(lr + 1));
    calB[0] = (short)0x3F80;                        // bf16 1.0
  }
  f32x4 cal = __builtin_amdgcn_mfma_f32_16x16x32_bf16(calA, calB, zero, 0, 0, 0);
  int rid[4];
#pragma unroll
  for (int j = 0; j < 4; ++j) {
    int v = (int)(cal[j] + 0.5f) - 1;
    rid[j] = v < 0 ? 0 : (v > 15 ? 15 : v);
  }

  const short8 a0 = *(const short8*)(tbf32 + (long)(row0 + lr) * 32 + g * 8);
  const short8 a1 = *(const short8*)(tbf32 + (long)(row0 + 16 + lr) * 32 + g * 8);
  f32x4 rmin0 = {3.4e38f, 3.4e38f, 3.4e38f, 3.4e38f};
  f32x4 rmin1 = rmin0;
#pragma unroll
  for (int s4 = 0; s4 < 4; ++s4) {                  // wave w: segs s4*4+w
    int code0 = (s4 * 4 + w) * 512;
#pragma unroll 2
    for (int t = 0; t < 32; ++t) {
      int code = code0 + t * 16 + lr;
      short8 b = *(const short8*)(cbf32 + (long)code * 32 + g * 8);
      f32x4 d0 = __builtin_amdgcn_mfma_f32_16x16x32_bf16(a0, b, zero, 0, 0, 0);
      f32x4 d1 = __builtin_amdgcn_mfma_f32_16x16x32_bf16(a1, b, zero, 0, 0, 0);
#pragma unroll
      for (int j = 0; j < 4; ++j) {
        rmin0[j] = fminf(rmin0[j], d0[j]);
        rmin1[j] = fminf(rmin1[j], d1[j]);
      }
    }
  }
  __syncthreads();                                  // rml init visible
  unsigned int* mywave = &rml[w * 33];
#pragma unroll
  for (int j = 0; j < 4; ++j) {
    atomicMin(&mywave[rid[j]],      encf(rmin0[j]));
    atomicMin(&mywave[16 + rid[j]], encf(rmin1[j]));
  }
  __syncthreads();
  if (tid < 32) {                                   // plain store (block-local)
    unsigned int mn = 0xFFFFFFFFu;
#pragma unroll
    for (int ww = 0; ww < 4; ++ww) mn = min(mn, rml[ww * 33 + tid]);
    rowmin_u[row0 + tid] = mn;
  }
}

// ---------------- Kernel 3: gatecp — gate + cproj fused (1 x 1024) -----------
__global__ __launch_bounds__(1024) void gatecp_kernel(
    const float* __restrict__ x, const float* __restrict__ W,
    const float* __restrict__ c2, const float* __restrict__ t2arr,
    const int* __restrict__ origrow, const unsigned int* __restrict__ rowmin_u,
    unsigned int* __restrict__ candcount, int* __restrict__ candlist,
    float* __restrict__ tgtm) {
  __shared__ float Wl[CDIM * D];                    // 20 KiB
  __shared__ float red_f[1024];
  __shared__ unsigned int cnt_s;
  int tid = threadIdx.x;

  for (int i = tid; i < (CDIM * D) / 4; i += 1024)
    ((float4*)Wl)[i] = ((const float4*)W)[i];
  float cm = 0.f;                                   // c2max
  for (int i = tid; i < NCODES; i += 1024) cm = fmaxf(cm, c2[i]);
  red_f[tid] = cm;
  if (tid == 0) cnt_s = 0u;
  __syncthreads();
  for (int s = 512; s > 0; s >>= 1) {
    if (tid < s) red_f[tid] = fmaxf(red_f[tid], red_f[tid + s]);
    __syncthreads();
  }
  float c2m = red_f[0];
  __syncthreads();
  float Tl = 3.4e38f;                               // T = min(a + eps)
  for (int i = tid; i < NMASK; i += 1024) {
    float a = decf(rowmin_u[i]);
    float e = fmaf(EPS_C, sqrtf(t2arr[i] * c2m), EPS_ABS);
    Tl = fminf(Tl, a + e);                          // NaN -> ignored
  }
  red_f[tid] = Tl;
  __syncthreads();
  for (int s = 512; s > 0; s >>= 1) {
    if (tid < s) red_f[tid] = fminf(red_f[tid], red_f[tid + s]);
    __syncthreads();
  }
  float T = red_f[0];
  for (int i = tid; i < NMASK; i += 1024) {         // candidates
    float a = decf(rowmin_u[i]);
    float e = fmaf(EPS_C, sqrtf(t2arr[i] * c2m), EPS_ABS);
    if (!(a - e > T)) {                             // NaN-safe: NaN -> candidate
      unsigned int pos = atomicAdd(&cnt_s, 1u);
      candlist[pos] = i;
    }
  }
  __syncthreads();
  int nc = (int)cnt_s;
  if (tid == 0) candcount[0] = cnt_s;               // plain store
  int grp = tid >> 3, ch = tid & 7;                 // cproj: 128 groups
  for (int idx = grp; idx < nc; idx += 128) {
    int row = origrow[candlist[idx]];
    float pd[16];
    proj_lds(x, Wl, row, ch, pd);                   // bit-identical chain
    if (ch == 0) {
      float* op = tgtm + (long)idx * 16;
#pragma unroll
      for (int c = 0; c < 16; ++c) op[c] = -2.0f * pd[c];
    }
  }
}

// ---------------- Kernel 4: rescore + rank emit (512 x 256, R14-verbatim) ----
__global__ __launch_bounds__(256) void rescore_kernel(
    const float* __restrict__ cbk, const float* __restrict__ c2,
    const float* __restrict__ tgtm, const float* __restrict__ t2arr,
    const int* __restrict__ origrow, const int* __restrict__ mask,
    const unsigned int* __restrict__ candcount, const int* __restrict__ candlist,
    unsigned long long* __restrict__ key, unsigned int* __restrict__ resctr,
    int* __restrict__ out) {
  __shared__ unsigned long long red[256];
  __shared__ int lastf;
  __shared__ unsigned int vlow_s;
  int tid = threadIdx.x, bid = (int)blockIdx.x;
  int nwork = (int)candcount[0] * 8;                // 8 octants x 1024 codes
  for (int wk = bid; wk < nwork; wk += (int)gridDim.x) {
    int ci = wk >> 3, oct = wk & 7;
    int r = candlist[ci];                           // slot, uniform per block
    float t2 = t2arr[r];
    int row = origrow[r];
    float tm[16];
    const float4* tp = (const float4*)(tgtm + (long)ci * 16);
#pragma unroll
    for (int q = 0; q < 4; ++q) {                   // uniform -> scalar loads
      float4 v = tp[q];
      tm[q*4+0] = v.x; tm[q*4+1] = v.y; tm[q*4+2] = v.z; tm[q*4+3] = v.w;
    }
    float minv = 3.4e38f; int mink = 0;
#pragma unroll 2
    for (int k = 0; k < 4; ++k) {                   // 4 codes/thread
      int code = oct * 1024 + k * 256 + tid;
      const float4* cp = (const float4*)(cbk + (long)code * CDIM);
      float4 c0 = cp[0], c1 = cp[1], c2v4 = cp[2], c3 = cp[3];
      float acc = fmaf(tm[0],  c0.x, c2[code]);
      acc = fmaf(tm[1],  c0.y, acc);   acc = fmaf(tm[2],  c0.z, acc);
      acc = fmaf(tm[3],  c0.w, acc);   acc = fmaf(tm[4],  c1.x, acc);
      acc = fmaf(tm[5],  c1.y, acc);   acc = fmaf(tm[6],  c1.z, acc);
      acc = fmaf(tm[7],  c1.w, acc);   acc = fmaf(tm[8],  c2v4.x, acc);
      acc = fmaf(tm[9],  c2v4.y, acc); acc = fmaf(tm[10], c2v4.z, acc);
      acc = fmaf(tm[11], c2v4.w, acc); acc = fmaf(tm[12], c3.x, acc);
      acc = fmaf(tm[13], c3.y, acc);   acc = fmaf(tm[14], c3.z, acc);
      acc = fmaf(tm[15], c3.w, acc);
      if (acc < minv) { minv = acc; mink = code; }
    }
    // tie-break on row*8192+code == lexicographic (row, code) == rank order
    red[tid] = ((unsigned long long)encf(t2 + minv) << 32)
        | (unsigned long long)((unsigned int)row * (unsigned int)NCODES + (unsigned int)mink);
    __syncthreads();
    for (int s = 128; s > 0; s >>= 1) {
      if (tid < s) { if (red[tid + s] < red[tid]) red[tid] = red[tid + s]; }
      __syncthreads();
    }
    if (tid == 0) atomicMin(key, red[0]);
    __syncthreads();                                // LDS reuse across wk
  }
  if (tid == 0) {
    __threadfence();
    lastf = (atomicAdd(resctr, 1u) == (unsigned int)gridDim.x - 1u) ? 1 : 0;
  }
  __syncthreads();
  if (lastf) {                                      // last block: rank + emit
    if (tid == 0)
      vlow_s = (unsigned int)(atomicMin(key, 0xFFFFFFFFFFFFFFFFull) & 0xFFFFFFFFull);
    __syncthreads();
    unsigned int vlow = vlow_s;
    int wrow = (int)(vlow >> 13), wcode = (int)(vlow & 8191u);
    int lo = tid * (NROWS / 256);
    int hi = lo + (NROWS / 256); if (hi > wrow) hi = wrow;
    int cnt = 0;
#pragma unroll 4
    for (int i = lo; i < hi; ++i) cnt += (mask[i] != 0);
    __shared__ int ps[256];
    ps[tid] = cnt;
    __syncthreads();
    for (int s = 128; s > 0; s >>= 1) {
      if (tid < s) ps[tid] += ps[tid + s];
      __syncthreads();
    }
    if (tid == 0) out[0] = ps[0] * NCODES + wcode;  // rank*8192 + code
  }
}

extern "C" void kernel_launch(void* const* d_in, const int* in_sizes, int n_in,
                              void* d_out, int out_size, void* d_ws, size_t ws_size,
                              hipStream_t stream) {
  const float* x    = (const float*)d_in[0];
  const int*   mask = (const int*)d_in[1];
  const float* W    = (const float*)d_in[2];
  const float* cbk  = (const float*)d_in[3];
  int* out = (int*)d_out;

  char* ws = (char*)d_ws;                                   // total 1,810,432 B (R6-proven)
  unsigned int*       ctrs      = (unsigned int*)(ws + 4096);
  unsigned int*       slotctr   = (unsigned int*)(ws + 4096);
  unsigned int*       resctr    = (unsigned int*)(ws + 4100);
  unsigned int*       candcount = (unsigned int*)(ws + 4112);       // gatecp stores
  unsigned long long* key       = (unsigned long long*)(ws + 8184); // init
  unsigned int*       rowmin_u  = (unsigned int*)(ws + 8192);       // 64 KiB
  float*              t2arr     = (float*)(ws + 73728);             // 64 KiB
  int*                origrow   = (int*)(ws + 139264);              // 64 KiB
  float*              c2        = (float*)(ws + 204800);            // 32 KiB
  unsigned short*     cbf32     = (unsigned short*)(ws + 237568);   // 512 KiB
  int*                candlist  = (int*)(ws + 237568);              // aliases cbf32 (dead by gatecp)
  unsigned short*     tbf32     = (unsigned short*)(ws + 761856);   // 1 MiB
  float*              tgtm      = (float*)(ws + 761856);            // aliases tbf32 (dead after phase1)

  init_kernel<<<1, 64, 0, stream>>>(ctrs, key);
  project_kernel<<<1024, 256, 0, stream>>>(x, mask, W, cbk, c2, cbf32, tbf32,
                                           t2arr, origrow, slotctr);
  phase1_kernel<<<512, 256, 0, stream>>>(tbf32, cbf32, rowmin_u);
  gatecp_kernel<<<1, 1024, 0, stream>>>(x, W, c2, t2arr, origrow, rowmin_u,
                                        candcount, candlist, tgtm);
  rescore_kernel<<<512, 256, 0, stream>>>(cbk, c2, tgtm, t2arr, origrow, mask,
                                          candcount, candlist, key, resctr, out);
}

// Round 18
// 115.706 us; speedup vs baseline: 1.0768x; 1.0001x over previous
//
#include <hip/hip_runtime.h>
#include <hip/hip_bf16.h>

// RandomProjectionQuantizer — R18: 2-level bf16 MFMA screen (nc collapse).
//  x:(16,2048,320) f32, mask:(16,2048) i32 (exactly 16384 ones),
//  W:(16,320) f32, codebook:(8192,16) f32 -> scalar int32 label
//
//  Screen computes FULL d^2 per output element via 3 accumulating MFMAs:
//    d = A.[c_hi,c_hi] + A.[c_lo,c_lo] + A_norm.B_norm,  A=[t_hi,t_lo]
//  (c stored as -2c hi/lo; norm pass = R5-proven fold with h/g bf16 splits
//  recomputed from exact f32 t2arr/c2). Screen error ~1.4e-3 -> candidate
//  window ~0.05 -> nc ~ 1-5 (was ~10^4: R17's 78us gatecp root cause).
//  Row attribution: runtime calibration MFMA (R6-proven). Rescore exact f32.

#define NMASK   16384
#define NROWS   32768
#define D       320
#define CDIM    16
#define NCODES  8192
#define EPS_C   2e-4f        // >> 2-level screen error coefficient (~3e-5)
#define EPS_ABS 0.02f

typedef __attribute__((ext_vector_type(8))) short short8;
typedef __attribute__((ext_vector_type(4))) float f32x4;

__device__ inline unsigned int encf(float f) {
  unsigned int u = __float_as_uint(f);
  return (u & 0x80000000u) ? ~u : (u | 0x80000000u);
}
__device__ inline float decf(unsigned int u) {
  unsigned int b = (u & 0x80000000u) ? (u & 0x7fffffffu) : ~u;
  return __uint_as_float(b);
}
__device__ inline unsigned short f2bf(float f) {   // RNE f32->bf16
  unsigned int u = __float_as_uint(f);
  unsigned int r = u + 0x7fffu + ((u >> 16) & 1u);
  return (unsigned short)(r >> 16);
}
__device__ inline float bf2f(unsigned short h) {
  return __uint_as_float(((unsigned int)h) << 16);
}

// LDS-W projection body (R12/R14-proven): lane ch covers d in {j*32+ch*4..+4},
// x prefetched (10-deep MLP), butterfly combine (xor 1,2,4).
__device__ inline void proj_lds(const float* __restrict__ x,
                                const float* __restrict__ Wl,
                                int row, int ch, float pd[16]) {
  const float* xr = x + (size_t)row * D + ch * 4;
  float4 xv[10];
#pragma unroll
  for (int j = 0; j < 10; ++j) xv[j] = *(const float4*)(xr + j * 32);
#pragma unroll
  for (int c = 0; c < 16; ++c) pd[c] = 0.f;
#pragma unroll
  for (int j = 0; j < 10; ++j) {
#pragma unroll
    for (int c = 0; c < 16; ++c) {
      const float4 wv = *(const float4*)&Wl[c * D + j * 32 + ch * 4];
      float acc = fmaf(xv[j].x, wv.x, pd[c]);
      acc = fmaf(xv[j].y, wv.y, acc);
      acc = fmaf(xv[j].z, wv.z, acc);
      pd[c] = fmaf(xv[j].w, wv.w, acc);
    }
  }
#pragma unroll
  for (int c = 0; c < 16; ++c) {
    pd[c] += __shfl_xor(pd[c], 1);
    pd[c] += __shfl_xor(pd[c], 2);
    pd[c] += __shfl_xor(pd[c], 4);
  }
}

// ---------------- Kernel 0: init (1 block x 64) ------------------------------
__global__ void init_kernel(unsigned int* __restrict__ ctrs,
                            unsigned long long* __restrict__ key) {
  if (threadIdx.x < 4) ctrs[threadIdx.x] = 0u;      // slotctr, resctr (+spare)
  if (threadIdx.x == 4) key[0] = 0xFFFFFFFFFFFFFFFFull;
}

// ---------------- Kernel 1: project (1024 blocks x 256) ----------------------
// Stores t as bf16 hi/lo pairs (tbf[slot][32] = [t_hi(16), t_lo(16)]);
// codes job stores -2c hi/lo (cbf[code][32] = [c_hi(16), c_lo(16)]) + c2.
__global__ __launch_bounds__(256) void project_kernel(
    const float* __restrict__ x, const int* __restrict__ mask,
    const float* __restrict__ W, const float* __restrict__ cbk,
    float* __restrict__ c2, unsigned short* __restrict__ cbf32,
    unsigned short* __restrict__ tbf32, float* __restrict__ t2arr,
    int* __restrict__ origrow, unsigned int* __restrict__ slotctr) {
  __shared__ float Wl[CDIM * D];                    // 20 KiB, natural layout
  __shared__ unsigned long long mb;
  __shared__ unsigned int wcnt[4], wbase[4];
  int tid = threadIdx.x, bid = (int)blockIdx.x;
  int chunk = bid >> 1, half = bid & 1;
  for (int i = tid; i < (CDIM * D) / 4; i += 256)
    ((float4*)Wl)[i] = ((const float4*)W)[i];
  if (tid < 64) {
    int m = mask[chunk * 64 + tid];
    unsigned long long bal = __ballot(m != 0);
    if (tid == 0) mb = bal;
  }
  __syncthreads();

  if (bid < 512 && tid < 16) {                      // codes job: -2c hi/lo + c2
    int k = bid * 16 + tid;
    const float4* p = (const float4*)(cbk + (long)k * CDIM);
    float s = 0.f; unsigned short chv[16], clv[16];
#pragma unroll
    for (int q = 0; q < 4; ++q) {
      float4 v = p[q];
      s = fmaf(v.x, v.x, s); s = fmaf(v.y, v.y, s);
      s = fmaf(v.z, v.z, s); s = fmaf(v.w, v.w, s);
      float m2[4] = {-2.0f * v.x, -2.0f * v.y, -2.0f * v.z, -2.0f * v.w};
#pragma unroll
      for (int e = 0; e < 4; ++e) {
        unsigned short hi = f2bf(m2[e]);
        chv[q*4+e] = hi;
        clv[q*4+e] = f2bf(m2[e] - bf2f(hi));
      }
    }
    c2[k] = s;
    uint4 pk0, pk1, pk2, pk3;
    pk0.x = (unsigned int)chv[0]  | ((unsigned int)chv[1]  << 16);
    pk0.y = (unsigned int)chv[2]  | ((unsigned int)chv[3]  << 16);
    pk0.z = (unsigned int)chv[4]  | ((unsigned int)chv[5]  << 16);
    pk0.w = (unsigned int)chv[6]  | ((unsigned int)chv[7]  << 16);
    pk1.x = (unsigned int)chv[8]  | ((unsigned int)chv[9]  << 16);
    pk1.y = (unsigned int)chv[10] | ((unsigned int)chv[11] << 16);
    pk1.z = (unsigned int)chv[12] | ((unsigned int)chv[13] << 16);
    pk1.w = (unsigned int)chv[14] | ((unsigned int)chv[15] << 16);
    pk2.x = (unsigned int)clv[0]  | ((unsigned int)clv[1]  << 16);
    pk2.y = (unsigned int)clv[2]  | ((unsigned int)clv[3]  << 16);
    pk2.z = (unsigned int)clv[4]  | ((unsigned int)clv[5]  << 16);
    pk2.w = (unsigned int)clv[6]  | ((unsigned int)clv[7]  << 16);
    pk3.x = (unsigned int)clv[8]  | ((unsigned int)clv[9]  << 16);
    pk3.y = (unsigned int)clv[10] | ((unsigned int)clv[11] << 16);
    pk3.z = (unsigned int)clv[12] | ((unsigned int)clv[13] << 16);
    pk3.w = (unsigned int)clv[14] | ((unsigned int)clv[15] << 16);
    uint4* dst = (uint4*)(cbf32 + (long)k * 32);
    dst[0] = pk0; dst[1] = pk1; dst[2] = pk2; dst[3] = pk3;
  }

  unsigned long long B0 = mb;
  int r = tid >> 3, ch = tid & 7, lane = tid & 63, w = tid >> 6;
  int p = half * 32 + r;                            // bit position in chunk
  int row = chunk * 64 + p;
  int m = (int)((B0 >> p) & 1ull);

  // per-BLOCK slot assignment: one atomicAdd per block (R13-proven)
  unsigned long long wbal = __ballot(m && ch == 0);
  if (lane == 0) wcnt[w] = (unsigned int)__popcll(wbal);
  __syncthreads();
  if (tid == 0) {
    unsigned int tot = wcnt[0] + wcnt[1] + wcnt[2] + wcnt[3];
    unsigned int b = tot ? atomicAdd(slotctr, tot) : 0u;
    wbase[0] = b;
    wbase[1] = b + wcnt[0];
    wbase[2] = b + wcnt[0] + wcnt[1];
    wbase[3] = b + wcnt[0] + wcnt[1] + wcnt[2];
  }
  __syncthreads();
  if (!m) return;                                   // no barriers past here

  float pd[16];
  proj_lds(x, Wl, row, ch, pd);                     // R12-proven body

  if (ch == 0) {
    int slot = (int)wbase[w] + __popcll(wbal & ((1ull << lane) - 1ull));
    float t2 = 0.f;
#pragma unroll
    for (int c = 0; c < 16; ++c) t2 = fmaf(pd[c], pd[c], t2);
    t2arr[slot] = t2;
    origrow[slot] = row;
    unsigned short th[16], tl[16];
#pragma unroll
    for (int c = 0; c < 16; ++c) {
      unsigned short hi = f2bf(pd[c]);
      th[c] = hi;
      tl[c] = f2bf(pd[c] - bf2f(hi));
    }
    uint4 pk0, pk1, pk2, pk3;
    pk0.x = (unsigned int)th[0]  | ((unsigned int)th[1]  << 16);
    pk0.y = (unsigned int)th[2]  | ((unsigned int)th[3]  << 16);
    pk0.z = (unsigned int)th[4]  | ((unsigned int)th[5]  << 16);
    pk0.w = (unsigned int)th[6]  | ((unsigned int)th[7]  << 16);
    pk1.x = (unsigned int)th[8]  | ((unsigned int)th[9]  << 16);
    pk1.y = (unsigned int)th[10] | ((unsigned int)th[11] << 16);
    pk1.z = (unsigned int)th[12] | ((unsigned int)th[13] << 16);
    pk1.w = (unsigned int)th[14] | ((unsigned int)th[15] << 16);
    pk2.x = (unsigned int)tl[0]  | ((unsigned int)tl[1]  << 16);
    pk2.y = (unsigned int)tl[2]  | ((unsigned int)tl[3]  << 16);
    pk2.z = (unsigned int)tl[4]  | ((unsigned int)tl[5]  << 16);
    pk2.w = (unsigned int)tl[6]  | ((unsigned int)tl[7]  << 16);
    pk3.x = (unsigned int)tl[8]  | ((unsigned int)tl[9]  << 16);
    pk3.y = (unsigned int)tl[10] | ((unsigned int)tl[11] << 16);
    pk3.z = (unsigned int)tl[12] | ((unsigned int)tl[13] << 16);
    pk3.w = (unsigned int)tl[14] | ((unsigned int)tl[15] << 16);
    uint4* dst = (uint4*)(tbf32 + (long)slot * 32);
    dst[0] = pk0; dst[1] = pk1; dst[2] = pk2; dst[3] = pk3;
  }
}

// ---------------- Kernel 2: 2-level MFMA screening (512 x 256) ---------------
// block = strip of 32 slots; wave w covers segs {s4*4+w}. Per 16-code block:
//   d = mfma(A,[c_hi,c_hi]) + mfma(A,[c_lo,c_lo]) + mfma(A_norm,B_norm)
// -> full d^2 per output element (error ~1.4e-3). Row-calib (R6-proven),
// per-strip minima plain-stored.
__global__ __launch_bounds__(256) void phase1_kernel(
    const unsigned short* __restrict__ tbf32,
    const unsigned short* __restrict__ cbf32,
    const float* __restrict__ t2arr, const float* __restrict__ c2,
    unsigned int* __restrict__ rowmin_u) {
  __shared__ unsigned int rml[4 * 33];
  int tid = threadIdx.x;
  int w = tid >> 6, l = tid & 63, lr = l & 15, g = l >> 4;
  int row0 = (int)blockIdx.x * 32;

  for (int i = tid; i < 4 * 33; i += 256) rml[i] = 0xFFFFFFFFu;

  const f32x4 zero = {0.f, 0.f, 0.f, 0.f};
  // row calibration (R6-proven)
  short8 calA = {0,0,0,0,0,0,0,0}, calB = {0,0,0,0,0,0,0,0};
  if (g == 0) {
    calA[0] = (short)f2bf((float)(lr + 1));
    calB[0] = (short)0x3F80;                        // bf16 1.0
  }
  f32x4 cal = __builtin_amdgcn_mfma_f32_16x16x32_bf16(calA, calB, zero, 0, 0, 0);
  int rid[4];
#pragma unroll
  for (int j = 0; j < 4; ++j) {
    int v = (int)(cal[j] + 0.5f) - 1;
    rid[j] = v < 0 ? 0 : (v > 15 ? 15 : v);
  }

  // A main: [t_hi(16), t_lo(16)] — lane (lr,g) reads its k-chunk directly.
  const short8 a0 = *(const short8*)(tbf32 + (long)(row0 + lr) * 32 + g * 8);
  const short8 a1 = *(const short8*)(tbf32 + (long)(row0 + 16 + lr) * 32 + g * 8);
  // A norm: rows [1, 1, h1, h2, 0...]; nonzero only in g==0 lanes (k=0..7).
  short8 an0 = {0,0,0,0,0,0,0,0}, an1 = {0,0,0,0,0,0,0,0};
  if (g == 0) {
    float t2a = t2arr[row0 + lr];
    float t2b = t2arr[row0 + 16 + lr];
    unsigned short h1a = f2bf(t2a), h2a = f2bf(t2a - bf2f(h1a));
    unsigned short h1b = f2bf(t2b), h2b = f2bf(t2b - bf2f(h1b));
    an0[0] = (short)0x3F80; an0[1] = (short)0x3F80;
    an0[2] = (short)h1a;    an0[3] = (short)h2a;
    an1[0] = (short)0x3F80; an1[1] = (short)0x3F80;
    an1[2] = (short)h1b;    an1[3] = (short)h2b;
  }

  f32x4 rmin0 = {3.4e38f, 3.4e38f, 3.4e38f, 3.4e38f};
  f32x4 rmin1 = rmin0;
#pragma unroll
  for (int s4 = 0; s4 < 4; ++s4) {                  // wave w: segs s4*4+w
    int code0 = (s4 * 4 + w) * 512;
    for (int t = 0; t < 32; ++t) {
      int code = code0 + t * 16 + lr;
      const unsigned short* cb = cbf32 + (long)code * 32;
      short8 bh = *(const short8*)(cb + ((g & 1) * 8));        // c_hi dup
      short8 bl = *(const short8*)(cb + 16 + ((g & 1) * 8));   // c_lo dup
      short8 bn = {0,0,0,0,0,0,0,0};
      if (g == 0) {                                 // B_norm col: [g1,g2,1,1,0..]
        float cc = c2[code];
        unsigned short g1 = f2bf(cc), g2 = f2bf(cc - bf2f(g1));
        bn[0] = (short)g1; bn[1] = (short)g2;
        bn[2] = (short)0x3F80; bn[3] = (short)0x3F80;
      }
      f32x4 d0 = __builtin_amdgcn_mfma_f32_16x16x32_bf16(a0, bh, zero, 0, 0, 0);
      d0 = __builtin_amdgcn_mfma_f32_16x16x32_bf16(a0, bl, d0, 0, 0, 0);
      d0 = __builtin_amdgcn_mfma_f32_16x16x32_bf16(an0, bn, d0, 0, 0, 0);
      f32x4 d1 = __builtin_amdgcn_mfma_f32_16x16x32_bf16(a1, bh, zero, 0, 0, 0);
      d1 = __builtin_amdgcn_mfma_f32_16x16x32_bf16(a1, bl, d1, 0, 0, 0);
      d1 = __builtin_amdgcn_mfma_f32_16x16x32_bf16(an1, bn, d1, 0, 0, 0);
#pragma unroll
      for (int j = 0; j < 4; ++j) {                 // d = full d^2 values
        rmin0[j] = fminf(rmin0[j], d0[j]);
        rmin1[j] = fminf(rmin1[j], d1[j]);
      }
    }
  }
  __syncthreads();                                  // rml init visible
  unsigned int* mywave = &rml[w * 33];
#pragma unroll
  for (int j = 0; j < 4; ++j) {
    atomicMin(&mywave[rid[j]],      encf(rmin0[j]));
    atomicMin(&mywave[16 + rid[j]], encf(rmin1[j]));
  }
  __syncthreads();
  if (tid < 32) {                                   // plain store (block-local)
    unsigned int mn = 0xFFFFFFFFu;
#pragma unroll
    for (int ww = 0; ww < 4; ++ww) mn = min(mn, rml[ww * 33 + tid]);
    rowmin_u[row0 + tid] = mn;
  }
}

// ---------------- Kernel 3: gate (1 block x 1024, lean) ----------------------
__global__ __launch_bounds__(1024) void gate_kernel(
    const unsigned int* __restrict__ rowmin_u, const float* __restrict__ t2arr,
    const float* __restrict__ c2,
    unsigned int* __restrict__ candcount, int* __restrict__ candlist) {
  __shared__ float red_f[1024];
  __shared__ unsigned int cnt_s;
  int tid = threadIdx.x;
  float cm = 0.f;                                   // c2max
  for (int i = tid; i < NCODES; i += 1024) cm = fmaxf(cm, c2[i]);
  red_f[tid] = cm;
  if (tid == 0) cnt_s = 0u;
  __syncthreads();
  for (int s = 512; s > 0; s >>= 1) {
    if (tid < s) red_f[tid] = fmaxf(red_f[tid], red_f[tid + s]);
    __syncthreads();
  }
  float c2m = red_f[0];
  __syncthreads();
  float Tl = 3.4e38f;                               // T = min(a + eps)
  for (int i = tid; i < NMASK; i += 1024) {
    float a = decf(rowmin_u[i]);
    float e = fmaf(EPS_C, sqrtf(t2arr[i] * c2m), EPS_ABS);
    Tl = fminf(Tl, a + e);                          // NaN -> ignored
  }
  red_f[tid] = Tl;
  __syncthreads();
  for (int s = 512; s > 0; s >>= 1) {
    if (tid < s) red_f[tid] = fminf(red_f[tid], red_f[tid + s]);
    __syncthreads();
  }
  float T = red_f[0];
  for (int i = tid; i < NMASK; i += 1024) {         // candidates
    float a = decf(rowmin_u[i]);
    float e = fmaf(EPS_C, sqrtf(t2arr[i] * c2m), EPS_ABS);
    if (!(a - e > T)) {                             // NaN-safe: NaN -> candidate
      unsigned int pos = atomicAdd(&cnt_s, 1u);
      candlist[pos] = i;
    }
  }
  __syncthreads();
  if (tid == 0) candcount[0] = cnt_s;               // plain store
}

// ---------------- Kernel 4: cproj (512 x 256, R14-proven early-exit) ---------
__global__ __launch_bounds__(256) void cproj_kernel(
    const float* __restrict__ x, const float* __restrict__ W,
    const int* __restrict__ origrow, const unsigned int* __restrict__ candcount,
    const int* __restrict__ candlist, float* __restrict__ tgtm) {
  int tid = threadIdx.x, bid = (int)blockIdx.x;
  int nc = (int)candcount[0];
  if (bid * 32 >= nc) return;                       // whole block idle
  __shared__ float Wl[CDIM * D];                    // 20 KiB
  for (int i = tid; i < (CDIM * D) / 4; i += 256)
    ((float4*)Wl)[i] = ((const float4*)W)[i];
  __syncthreads();
  int idx = bid * 32 + (tid >> 3);                  // candidate index
  int ch  = tid & 7;
  if (idx >= nc) return;
  int row = origrow[candlist[idx]];
  float pd[16];
  proj_lds(x, Wl, row, ch, pd);                     // bit-identical chain
  if (ch == 0) {
    float* op = tgtm + (long)idx * 16;
#pragma unroll
    for (int c = 0; c < 16; ++c) op[c] = -2.0f * pd[c];
  }
}

// ---------------- Kernel 5: rescore + rank emit (512 x 256, R17-verbatim) ----
__global__ __launch_bounds__(256) void rescore_kernel(
    const float* __restrict__ cbk, const float* __restrict__ c2,
    const float* __restrict__ tgtm, const float* __restrict__ t2arr,
    const int* __restrict__ origrow, const int* __restrict__ mask,
    const unsigned int* __restrict__ candcount, const int* __restrict__ candlist,
    unsigned long long* __restrict__ key, unsigned int* __restrict__ resctr,
    int* __restrict__ out) {
  __shared__ unsigned long long red[256];
  __shared__ int lastf;
  __shared__ unsigned int vlow_s;
  int tid = threadIdx.x, bid = (int)blockIdx.x;
  int nwork = (int)candcount[0] * 8;                // 8 octants x 1024 codes
  for (int wk = bid; wk < nwork; wk += (int)gridDim.x) {
    int ci = wk >> 3, oct = wk & 7;
    int r = candlist[ci];                           // slot, uniform per block
    float t2 = t2arr[r];
    int row = origrow[r];
    float tm[16];
    const float4* tp = (const float4*)(tgtm + (long)ci * 16);
#pragma unroll
    for (int q = 0; q < 4; ++q) {                   // uniform -> scalar loads
      float4 v = tp[q];
      tm[q*4+0] = v.x; tm[q*4+1] = v.y; tm[q*4+2] = v.z; tm[q*4+3] = v.w;
    }
    float minv = 3.4e38f; int mink = 0;
#pragma unroll 2
    for (int k = 0; k < 4; ++k) {                   // 4 codes/thread
      int code = oct * 1024 + k * 256 + tid;
      const float4* cp = (const float4*)(cbk + (long)code * CDIM);
      float4 c0 = cp[0], c1 = cp[1], c2v4 = cp[2], c3 = cp[3];
      float acc = fmaf(tm[0],  c0.x, c2[code]);
      acc = fmaf(tm[1],  c0.y, acc);   acc = fmaf(tm[2],  c0.z, acc);
      acc = fmaf(tm[3],  c0.w, acc);   acc = fmaf(tm[4],  c1.x, acc);
      acc = fmaf(tm[5],  c1.y, acc);   acc = fmaf(tm[6],  c1.z, acc);
      acc = fmaf(tm[7],  c1.w, acc);   acc = fmaf(tm[8],  c2v4.x, acc);
      acc = fmaf(tm[9],  c2v4.y, acc); acc = fmaf(tm[10], c2v4.z, acc);
      acc = fmaf(tm[11], c2v4.w, acc); acc = fmaf(tm[12], c3.x, acc);
      acc = fmaf(tm[13], c3.y, acc);   acc = fmaf(tm[14], c3.z, acc);
      acc = fmaf(tm[15], c3.w, acc);
      if (acc < minv) { minv = acc; mink = code; }
    }
    // tie-break on row*8192+code == lexicographic (row, code) == rank order
    red[tid] = ((unsigned long long)encf(t2 + minv) << 32)
        | (unsigned long long)((unsigned int)row * (unsigned int)NCODES + (unsigned int)mink);
    __syncthreads();
    for (int s = 128; s > 0; s >>= 1) {
      if (tid < s) { if (red[tid + s] < red[tid]) red[tid] = red[tid + s]; }
      __syncthreads();
    }
    if (tid == 0) atomicMin(key, red[0]);
    __syncthreads();                                // LDS reuse across wk
  }
  if (tid == 0) {
    __threadfence();
    lastf = (atomicAdd(resctr, 1u) == (unsigned int)gridDim.x - 1u) ? 1 : 0;
  }
  __syncthreads();
  if (lastf) {                                      // last block: rank + emit
    if (tid == 0)
      vlow_s = (unsigned int)(atomicMin(key, 0xFFFFFFFFFFFFFFFFull) & 0xFFFFFFFFull);
    __syncthreads();
    unsigned int vlow = vlow_s;
    int wrow = (int)(vlow >> 13), wcode = (int)(vlow & 8191u);
    int lo = tid * (NROWS / 256);
    int hi = lo + (NROWS / 256); if (hi > wrow) hi = wrow;
    int cnt = 0;
#pragma unroll 4
    for (int i = lo; i < hi; ++i) cnt += (mask[i] != 0);
    __shared__ int ps[256];
    ps[tid] = cnt;
    __syncthreads();
    for (int s = 128; s > 0; s >>= 1) {
      if (tid < s) ps[tid] += ps[tid + s];
      __syncthreads();
    }
    if (tid == 0) out[0] = ps[0] * NCODES + wcode;  // rank*8192 + code
  }
}

extern "C" void kernel_launch(void* const* d_in, const int* in_sizes, int n_in,
                              void* d_out, int out_size, void* d_ws, size_t ws_size,
                              hipStream_t stream) {
  const float* x    = (const float*)d_in[0];
  const int*   mask = (const int*)d_in[1];
  const float* W    = (const float*)d_in[2];
  const float* cbk  = (const float*)d_in[3];
  int* out = (int*)d_out;

  char* ws = (char*)d_ws;                                   // total 1,810,432 B (R6-proven)
  unsigned int*       ctrs      = (unsigned int*)(ws + 4096);
  unsigned int*       slotctr   = (unsigned int*)(ws + 4096);
  unsigned int*       resctr    = (unsigned int*)(ws + 4100);
  unsigned int*       candcount = (unsigned int*)(ws + 4112);       // gate stores
  unsigned long long* key       = (unsigned long long*)(ws + 8184); // init
  unsigned int*       rowmin_u  = (unsigned int*)(ws + 8192);       // 64 KiB
  float*              t2arr     = (float*)(ws + 73728);             // 64 KiB
  int*                origrow   = (int*)(ws + 139264);              // 64 KiB
  float*              c2        = (float*)(ws + 204800);            // 32 KiB
  unsigned short*     cbf32     = (unsigned short*)(ws + 237568);   // 512 KiB
  int*                candlist  = (int*)(ws + 237568);              // aliases cbf32 (dead by gate)
  unsigned short*     tbf32     = (unsigned short*)(ws + 761856);   // 1 MiB
  float*              tgtm      = (float*)(ws + 761856);            // aliases tbf32 (dead after phase1)

  init_kernel<<<1, 64, 0, stream>>>(ctrs, key);
  project_kernel<<<1024, 256, 0, stream>>>(x, mask, W, cbk, c2, cbf32, tbf32,
                                           t2arr, origrow, slotctr);
  phase1_kernel<<<512, 256, 0, stream>>>(tbf32, cbf32, t2arr, c2, rowmin_u);
  gate_kernel<<<1, 1024, 0, stream>>>(rowmin_u, t2arr, c2, candcount, candlist);
  cproj_kernel<<<512, 256, 0, stream>>>(x, W, origrow, candcount, candlist, tgtm);
  rescore_kernel<<<512, 256, 0, stream>>>(cbk, c2, tgtm, t2arr, origrow, mask,
                                          candcount, candlist, key, resctr, out);
}

// Round 19
// 104.524 us; speedup vs baseline: 1.1920x; 1.1070x over previous
//
#include <hip/hip_runtime.h>
#include <hip/hip_bf16.h>

// RandomProjectionQuantizer — R19: 2-MFMA fused screen, 64-row blocks.
//  x:(16,2048,320) f32, mask:(16,2048) i32 (exactly 16384 ones),
//  W:(16,320) f32, codebook:(8192,16) f32 -> scalar int32 label
//
//  Screen per 16-code block now = 2 accumulating MFMAs (was 3):
//    D = A1.[c_hi,c_hi] + A2.B2,  A1=[t_hi,t_lo], A2=[t_hi | 1,1,h1,h2,0..],
//    B2=[c_lo | g1,g2,1,1,0..]  -> full d^2 minus negligible t_lo.c_lo.
//  (g1,g2) precomputed per code in project (cnrm). phase1: 256 blocks x 512,
//  block = 64 rows, wave = 1024 codes, 4 independent 2-MFMA chains per load.
//  All other kernels R18-verbatim (proven).

#define NMASK   16384
#define NROWS   32768
#define D       320
#define CDIM    16
#define NCODES  8192
#define EPS_C   2e-4f        // >> 2-level screen error coefficient (~1e-5)
#define EPS_ABS 0.02f

typedef __attribute__((ext_vector_type(8))) short short8;
typedef __attribute__((ext_vector_type(4))) float f32x4;

__device__ inline unsigned int encf(float f) {
  unsigned int u = __float_as_uint(f);
  return (u & 0x80000000u) ? ~u : (u | 0x80000000u);
}
__device__ inline float decf(unsigned int u) {
  unsigned int b = (u & 0x80000000u) ? (u & 0x7fffffffu) : ~u;
  return __uint_as_float(b);
}
__device__ inline unsigned short f2bf(float f) {   // RNE f32->bf16
  unsigned int u = __float_as_uint(f);
  unsigned int r = u + 0x7fffu + ((u >> 16) & 1u);
  return (unsigned short)(r >> 16);
}
__device__ inline float bf2f(unsigned short h) {
  return __uint_as_float(((unsigned int)h) << 16);
}

// LDS-W projection body (R12/R14-proven).
__device__ inline void proj_lds(const float* __restrict__ x,
                                const float* __restrict__ Wl,
                                int row, int ch, float pd[16]) {
  const float* xr = x + (size_t)row * D + ch * 4;
  float4 xv[10];
#pragma unroll
  for (int j = 0; j < 10; ++j) xv[j] = *(const float4*)(xr + j * 32);
#pragma unroll
  for (int c = 0; c < 16; ++c) pd[c] = 0.f;
#pragma unroll
  for (int j = 0; j < 10; ++j) {
#pragma unroll
    for (int c = 0; c < 16; ++c) {
      const float4 wv = *(const float4*)&Wl[c * D + j * 32 + ch * 4];
      float acc = fmaf(xv[j].x, wv.x, pd[c]);
      acc = fmaf(xv[j].y, wv.y, acc);
      acc = fmaf(xv[j].z, wv.z, acc);
      pd[c] = fmaf(xv[j].w, wv.w, acc);
    }
  }
#pragma unroll
  for (int c = 0; c < 16; ++c) {
    pd[c] += __shfl_xor(pd[c], 1);
    pd[c] += __shfl_xor(pd[c], 2);
    pd[c] += __shfl_xor(pd[c], 4);
  }
}

// ---------------- Kernel 0: init (1 block x 64) ------------------------------
__global__ void init_kernel(unsigned int* __restrict__ ctrs,
                            unsigned long long* __restrict__ key) {
  if (threadIdx.x < 4) ctrs[threadIdx.x] = 0u;      // slotctr, resctr (+spare)
  if (threadIdx.x == 4) key[0] = 0xFFFFFFFFFFFFFFFFull;
}

// ---------------- Kernel 1: project (1024 blocks x 256) ----------------------
// t as bf16 hi/lo pairs; codes job: -2c hi/lo + c2 + cnrm=(g1|g2<<16).
__global__ __launch_bounds__(256) void project_kernel(
    const float* __restrict__ x, const int* __restrict__ mask,
    const float* __restrict__ W, const float* __restrict__ cbk,
    float* __restrict__ c2, unsigned int* __restrict__ cnrm,
    unsigned short* __restrict__ cbf32, unsigned short* __restrict__ tbf32,
    float* __restrict__ t2arr, int* __restrict__ origrow,
    unsigned int* __restrict__ slotctr) {
  __shared__ float Wl[CDIM * D];                    // 20 KiB, natural layout
  __shared__ unsigned long long mb;
  __shared__ unsigned int wcnt[4], wbase[4];
  int tid = threadIdx.x, bid = (int)blockIdx.x;
  int chunk = bid >> 1, half = bid & 1;
  for (int i = tid; i < (CDIM * D) / 4; i += 256)
    ((float4*)Wl)[i] = ((const float4*)W)[i];
  if (tid < 64) {
    int m = mask[chunk * 64 + tid];
    unsigned long long bal = __ballot(m != 0);
    if (tid == 0) mb = bal;
  }
  __syncthreads();

  if (bid < 512 && tid < 16) {                      // codes job
    int k = bid * 16 + tid;
    const float4* p = (const float4*)(cbk + (long)k * CDIM);
    float s = 0.f; unsigned short chv[16], clv[16];
#pragma unroll
    for (int q = 0; q < 4; ++q) {
      float4 v = p[q];
      s = fmaf(v.x, v.x, s); s = fmaf(v.y, v.y, s);
      s = fmaf(v.z, v.z, s); s = fmaf(v.w, v.w, s);
      float m2[4] = {-2.0f * v.x, -2.0f * v.y, -2.0f * v.z, -2.0f * v.w};
#pragma unroll
      for (int e = 0; e < 4; ++e) {
        unsigned short hi = f2bf(m2[e]);
        chv[q*4+e] = hi;
        clv[q*4+e] = f2bf(m2[e] - bf2f(hi));
      }
    }
    c2[k] = s;
    unsigned short g1 = f2bf(s), g2 = f2bf(s - bf2f(g1));
    cnrm[k] = (unsigned int)g1 | ((unsigned int)g2 << 16);
    uint4 pk0, pk1, pk2, pk3;
    pk0.x = (unsigned int)chv[0]  | ((unsigned int)chv[1]  << 16);
    pk0.y = (unsigned int)chv[2]  | ((unsigned int)chv[3]  << 16);
    pk0.z = (unsigned int)chv[4]  | ((unsigned int)chv[5]  << 16);
    pk0.w = (unsigned int)chv[6]  | ((unsigned int)chv[7]  << 16);
    pk1.x = (unsigned int)chv[8]  | ((unsigned int)chv[9]  << 16);
    pk1.y = (unsigned int)chv[10] | ((unsigned int)chv[11] << 16);
    pk1.z = (unsigned int)chv[12] | ((unsigned int)chv[13] << 16);
    pk1.w = (unsigned int)chv[14] | ((unsigned int)chv[15] << 16);
    pk2.x = (unsigned int)clv[0]  | ((unsigned int)clv[1]  << 16);
    pk2.y = (unsigned int)clv[2]  | ((unsigned int)clv[3]  << 16);
    pk2.z = (unsigned int)clv[4]  | ((unsigned int)clv[5]  << 16);
    pk2.w = (unsigned int)clv[6]  | ((unsigned int)clv[7]  << 16);
    pk3.x = (unsigned int)clv[8]  | ((unsigned int)clv[9]  << 16);
    pk3.y = (unsigned int)clv[10] | ((unsigned int)clv[11] << 16);
    pk3.z = (unsigned int)clv[12] | ((unsigned int)clv[13] << 16);
    pk3.w = (unsigned int)clv[14] | ((unsigned int)clv[15] << 16);
    uint4* dst = (uint4*)(cbf32 + (long)k * 32);
    dst[0] = pk0; dst[1] = pk1; dst[2] = pk2; dst[3] = pk3;
  }

  unsigned long long B0 = mb;
  int r = tid >> 3, ch = tid & 7, lane = tid & 63, w = tid >> 6;
  int p = half * 32 + r;                            // bit position in chunk
  int row = chunk * 64 + p;
  int m = (int)((B0 >> p) & 1ull);

  unsigned long long wbal = __ballot(m && ch == 0);
  if (lane == 0) wcnt[w] = (unsigned int)__popcll(wbal);
  __syncthreads();
  if (tid == 0) {
    unsigned int tot = wcnt[0] + wcnt[1] + wcnt[2] + wcnt[3];
    unsigned int b = tot ? atomicAdd(slotctr, tot) : 0u;
    wbase[0] = b;
    wbase[1] = b + wcnt[0];
    wbase[2] = b + wcnt[0] + wcnt[1];
    wbase[3] = b + wcnt[0] + wcnt[1] + wcnt[2];
  }
  __syncthreads();
  if (!m) return;

  float pd[16];
  proj_lds(x, Wl, row, ch, pd);                     // R12-proven body

  if (ch == 0) {
    int slot = (int)wbase[w] + __popcll(wbal & ((1ull << lane) - 1ull));
    float t2 = 0.f;
#pragma unroll
    for (int c = 0; c < 16; ++c) t2 = fmaf(pd[c], pd[c], t2);
    t2arr[slot] = t2;
    origrow[slot] = row;
    unsigned short th[16], tl[16];
#pragma unroll
    for (int c = 0; c < 16; ++c) {
      unsigned short hi = f2bf(pd[c]);
      th[c] = hi;
      tl[c] = f2bf(pd[c] - bf2f(hi));
    }
    uint4 pk0, pk1, pk2, pk3;
    pk0.x = (unsigned int)th[0]  | ((unsigned int)th[1]  << 16);
    pk0.y = (unsigned int)th[2]  | ((unsigned int)th[3]  << 16);
    pk0.z = (unsigned int)th[4]  | ((unsigned int)th[5]  << 16);
    pk0.w = (unsigned int)th[6]  | ((unsigned int)th[7]  << 16);
    pk1.x = (unsigned int)th[8]  | ((unsigned int)th[9]  << 16);
    pk1.y = (unsigned int)th[10] | ((unsigned int)th[11] << 16);
    pk1.z = (unsigned int)th[12] | ((unsigned int)th[13] << 16);
    pk1.w = (unsigned int)th[14] | ((unsigned int)th[15] << 16);
    pk2.x = (unsigned int)tl[0]  | ((unsigned int)tl[1]  << 16);
    pk2.y = (unsigned int)tl[2]  | ((unsigned int)tl[3]  << 16);
    pk2.z = (unsigned int)tl[4]  | ((unsigned int)tl[5]  << 16);
    pk2.w = (unsigned int)tl[6]  | ((unsigned int)tl[7]  << 16);
    pk3.x = (unsigned int)tl[8]  | ((unsigned int)tl[9]  << 16);
    pk3.y = (unsigned int)tl[10] | ((unsigned int)tl[11] << 16);
    pk3.z = (unsigned int)tl[12] | ((unsigned int)tl[13] << 16);
    pk3.w = (unsigned int)tl[14] | ((unsigned int)tl[15] << 16);
    uint4* dst = (uint4*)(tbf32 + (long)slot * 32);
    dst[0] = pk0; dst[1] = pk1; dst[2] = pk2; dst[3] = pk3;
  }
}

// ---------------- Kernel 2: 2-MFMA screening (256 blocks x 512) --------------
// block = 64 rows (4 groups of 16); wave w covers codes [w*1024,(w+1)*1024).
// Per 16-code block: 4 independent chains of 2 accumulating MFMAs.
__global__ __launch_bounds__(512) void phase1_kernel(
    const unsigned short* __restrict__ tbf32,
    const unsigned short* __restrict__ cbf32,
    const unsigned int* __restrict__ cnrm,
    const float* __restrict__ t2arr,
    unsigned int* __restrict__ rowmin_u) {
  __shared__ unsigned int rml[8 * 65];
  int tid = threadIdx.x;
  int w = tid >> 6, l = tid & 63, lr = l & 15, g = l >> 4;
  int row0 = (int)blockIdx.x * 64;

  for (int i = tid; i < 8 * 65; i += 512) rml[i] = 0xFFFFFFFFu;

  const f32x4 zero = {0.f, 0.f, 0.f, 0.f};
  // row calibration (R6-proven)
  short8 calA = {0,0,0,0,0,0,0,0}, calB = {0,0,0,0,0,0,0,0};
  if (g == 0) {
    calA[0] = (short)f2bf((float)(lr + 1));
    calB[0] = (short)0x3F80;                        // bf16 1.0
  }
  f32x4 cal = __builtin_amdgcn_mfma_f32_16x16x32_bf16(calA, calB, zero, 0, 0, 0);
  int rid[4];
#pragma unroll
  for (int j = 0; j < 4; ++j) {
    int v = (int)(cal[j] + 0.5f) - 1;
    rid[j] = v < 0 ? 0 : (v > 15 ? 15 : v);
  }

  // A operands for 4 row groups
  short8 a1[4], a2[4];
  f32x4 rmin[4];
#pragma unroll
  for (int rg = 0; rg < 4; ++rg) {
    int row = row0 + rg * 16 + lr;
    a1[rg] = *(const short8*)(tbf32 + (long)row * 32 + g * 8);  // [t_hi,t_lo] chunk g
    short8 t = {0,0,0,0,0,0,0,0};
    if (g < 2) {
      t = a1[rg];                                   // t_hi chunks
    } else if (g == 2) {                            // [1,1,h1,h2,0...] at k=16..23
      float t2v = t2arr[row];
      unsigned short h1 = f2bf(t2v), h2 = f2bf(t2v - bf2f(h1));
      t[0] = (short)0x3F80; t[1] = (short)0x3F80;
      t[2] = (short)h1;     t[3] = (short)h2;
    }
    a2[rg] = t;
    rmin[rg] = (f32x4){3.4e38f, 3.4e38f, 3.4e38f, 3.4e38f};
  }

  int cbase = w * 1024;
#pragma unroll 2
  for (int t = 0; t < 64; ++t) {
    int code = cbase + t * 16 + lr;
    const unsigned short* cb = cbf32 + (long)code * 32;
    short8 bh = *(const short8*)(cb + (g & 1) * 8); // [c_hi,c_hi] dup
    short8 b2 = {0,0,0,0,0,0,0,0};
    if (g < 2) {
      b2 = *(const short8*)(cb + 16 + g * 8);       // c_lo chunks at k=0..15
    } else if (g == 2) {                            // [g1,g2,1,1,0..] at k=16..23
      unsigned int cn = cnrm[code];
      b2[0] = (short)(cn & 0xFFFFu);
      b2[1] = (short)(cn >> 16);
      b2[2] = (short)0x3F80; b2[3] = (short)0x3F80;
    }
#pragma unroll
    for (int rg = 0; rg < 4; ++rg) {                // 4 independent 2-chains
      f32x4 d = __builtin_amdgcn_mfma_f32_16x16x32_bf16(a1[rg], bh, zero, 0, 0, 0);
      d = __builtin_amdgcn_mfma_f32_16x16x32_bf16(a2[rg], b2, d, 0, 0, 0);
#pragma unroll
      for (int j = 0; j < 4; ++j) rmin[rg][j] = fminf(rmin[rg][j], d[j]);
    }
  }
  __syncthreads();                                  // rml init complete
  unsigned int* myw = &rml[w * 65];
#pragma unroll
  for (int rg = 0; rg < 4; ++rg)
#pragma unroll
    for (int j = 0; j < 4; ++j)
      atomicMin(&myw[rg * 16 + rid[j]], encf(rmin[rg][j]));
  __syncthreads();
  if (tid < 64) {                                   // merge 8 waves, plain store
    unsigned int mn = 0xFFFFFFFFu;
#pragma unroll
    for (int ww = 0; ww < 8; ++ww) mn = min(mn, rml[ww * 65 + tid]);
    rowmin_u[row0 + tid] = mn;
  }
}

// ---------------- Kernel 3: gate (1 block x 1024, R18-verbatim) --------------
__global__ __launch_bounds__(1024) void gate_kernel(
    const unsigned int* __restrict__ rowmin_u, const float* __restrict__ t2arr,
    const float* __restrict__ c2,
    unsigned int* __restrict__ candcount, int* __restrict__ candlist) {
  __shared__ float red_f[1024];
  __shared__ unsigned int cnt_s;
  int tid = threadIdx.x;
  float cm = 0.f;                                   // c2max
  for (int i = tid; i < NCODES; i += 1024) cm = fmaxf(cm, c2[i]);
  red_f[tid] = cm;
  if (tid == 0) cnt_s = 0u;
  __syncthreads();
  for (int s = 512; s > 0; s >>= 1) {
    if (tid < s) red_f[tid] = fmaxf(red_f[tid], red_f[tid + s]);
    __syncthreads();
  }
  float c2m = red_f[0];
  __syncthreads();
  float Tl = 3.4e38f;                               // T = min(a + eps)
  for (int i = tid; i < NMASK; i += 1024) {
    float a = decf(rowmin_u[i]);
    float e = fmaf(EPS_C, sqrtf(t2arr[i] * c2m), EPS_ABS);
    Tl = fminf(Tl, a + e);                          // NaN -> ignored
  }
  red_f[tid] = Tl;
  __syncthreads();
  for (int s = 512; s > 0; s >>= 1) {
    if (tid < s) red_f[tid] = fminf(red_f[tid], red_f[tid + s]);
    __syncthreads();
  }
  float T = red_f[0];
  for (int i = tid; i < NMASK; i += 1024) {         // candidates
    float a = decf(rowmin_u[i]);
    float e = fmaf(EPS_C, sqrtf(t2arr[i] * c2m), EPS_ABS);
    if (!(a - e > T)) {                             // NaN-safe: NaN -> candidate
      unsigned int pos = atomicAdd(&cnt_s, 1u);
      candlist[pos] = i;
    }
  }
  __syncthreads();
  if (tid == 0) candcount[0] = cnt_s;               // plain store
}

// ---------------- Kernel 4: cproj (512 x 256, R18-verbatim) ------------------
__global__ __launch_bounds__(256) void cproj_kernel(
    const float* __restrict__ x, const float* __restrict__ W,
    const int* __restrict__ origrow, const unsigned int* __restrict__ candcount,
    const int* __restrict__ candlist, float* __restrict__ tgtm) {
  int tid = threadIdx.x, bid = (int)blockIdx.x;
  int nc = (int)candcount[0];
  if (bid * 32 >= nc) return;                       // whole block idle
  __shared__ float Wl[CDIM * D];                    // 20 KiB
  for (int i = tid; i < (CDIM * D) / 4; i += 256)
    ((float4*)Wl)[i] = ((const float4*)W)[i];
  __syncthreads();
  int idx = bid * 32 + (tid >> 3);                  // candidate index
  int ch  = tid & 7;
  if (idx >= nc) return;
  int row = origrow[candlist[idx]];
  float pd[16];
  proj_lds(x, Wl, row, ch, pd);                     // bit-identical chain
  if (ch == 0) {
    float* op = tgtm + (long)idx * 16;
#pragma unroll
    for (int c = 0; c < 16; ++c) op[c] = -2.0f * pd[c];
  }
}

// ---------------- Kernel 5: rescore + rank emit (512 x 256, R18-verbatim) ----
__global__ __launch_bounds__(256) void rescore_kernel(
    const float* __restrict__ cbk, const float* __restrict__ c2,
    const float* __restrict__ tgtm, const float* __restrict__ t2arr,
    const int* __restrict__ origrow, const int* __restrict__ mask,
    const unsigned int* __restrict__ candcount, const int* __restrict__ candlist,
    unsigned long long* __restrict__ key, unsigned int* __restrict__ resctr,
    int* __restrict__ out) {
  __shared__ unsigned long long red[256];
  __shared__ int lastf;
  __shared__ unsigned int vlow_s;
  int tid = threadIdx.x, bid = (int)blockIdx.x;
  int nwork = (int)candcount[0] * 8;                // 8 octants x 1024 codes
  for (int wk = bid; wk < nwork; wk += (int)gridDim.x) {
    int ci = wk >> 3, oct = wk & 7;
    int r = candlist[ci];                           // slot, uniform per block
    float t2 = t2arr[r];
    int row = origrow[r];
    float tm[16];
    const float4* tp = (const float4*)(tgtm + (long)ci * 16);
#pragma unroll
    for (int q = 0; q < 4; ++q) {                   // uniform -> scalar loads
      float4 v = tp[q];
      tm[q*4+0] = v.x; tm[q*4+1] = v.y; tm[q*4+2] = v.z; tm[q*4+3] = v.w;
    }
    float minv = 3.4e38f; int mink = 0;
#pragma unroll 2
    for (int k = 0; k < 4; ++k) {                   // 4 codes/thread
      int code = oct * 1024 + k * 256 + tid;
      const float4* cp = (const float4*)(cbk + (long)code * CDIM);
      float4 c0 = cp[0], c1 = cp[1], c2v4 = cp[2], c3 = cp[3];
      float acc = fmaf(tm[0],  c0.x, c2[code]);
      acc = fmaf(tm[1],  c0.y, acc);   acc = fmaf(tm[2],  c0.z, acc);
      acc = fmaf(tm[3],  c0.w, acc);   acc = fmaf(tm[4],  c1.x, acc);
      acc = fmaf(tm[5],  c1.y, acc);   acc = fmaf(tm[6],  c1.z, acc);
      acc = fmaf(tm[7],  c1.w, acc);   acc = fmaf(tm[8],  c2v4.x, acc);
      acc = fmaf(tm[9],  c2v4.y, acc); acc = fmaf(tm[10], c2v4.z, acc);
      acc = fmaf(tm[11], c2v4.w, acc); acc = fmaf(tm[12], c3.x, acc);
      acc = fmaf(tm[13], c3.y, acc);   acc = fmaf(tm[14], c3.z, acc);
      acc = fmaf(tm[15], c3.w, acc);
      if (acc < minv) { minv = acc; mink = code; }
    }
    // tie-break on row*8192+code == lexicographic (row, code) == rank order
    red[tid] = ((unsigned long long)encf(t2 + minv) << 32)
        | (unsigned long long)((unsigned int)row * (unsigned int)NCODES + (unsigned int)mink);
    __syncthreads();
    for (int s = 128; s > 0; s >>= 1) {
      if (tid < s) { if (red[tid + s] < red[tid]) red[tid] = red[tid + s]; }
      __syncthreads();
    }
    if (tid == 0) atomicMin(key, red[0]);
    __syncthreads();                                // LDS reuse across wk
  }
  if (tid == 0) {
    __threadfence();
    lastf = (atomicAdd(resctr, 1u) == (unsigned int)gridDim.x - 1u) ? 1 : 0;
  }
  __syncthreads();
  if (lastf) {                                      // last block: rank + emit
    if (tid == 0)
      vlow_s = (unsigned int)(atomicMin(key, 0xFFFFFFFFFFFFFFFFull) & 0xFFFFFFFFull);
    __syncthreads();
    unsigned int vlow = vlow_s;
    int wrow = (int)(vlow >> 13), wcode = (int)(vlow & 8191u);
    int lo = tid * (NROWS / 256);
    int hi = lo + (NROWS / 256); if (hi > wrow) hi = wrow;
    int cnt = 0;
#pragma unroll 4
    for (int i = lo; i < hi; ++i) cnt += (mask[i] != 0);
    __shared__ int ps[256];
    ps[tid] = cnt;
    __syncthreads();
    for (int s = 128; s > 0; s >>= 1) {
      if (tid < s) ps[tid] += ps[tid + s];
      __syncthreads();
    }
    if (tid == 0) out[0] = ps[0] * NCODES + wcode;  // rank*8192 + code
  }
}

extern "C" void kernel_launch(void* const* d_in, const int* in_sizes, int n_in,
                              void* d_out, int out_size, void* d_ws, size_t ws_size,
                              hipStream_t stream) {
  const float* x    = (const float*)d_in[0];
  const int*   mask = (const int*)d_in[1];
  const float* W    = (const float*)d_in[2];
  const float* cbk  = (const float*)d_in[3];
  int* out = (int*)d_out;

  char* ws = (char*)d_ws;                            // total 1,843,200 B (< proven ~2.0 MB, R3/R4)
  unsigned int*       ctrs      = (unsigned int*)(ws + 4096);
  unsigned int*       slotctr   = (unsigned int*)(ws + 4096);
  unsigned int*       resctr    = (unsigned int*)(ws + 4100);
  unsigned int*       candcount = (unsigned int*)(ws + 4112);       // gate stores
  unsigned long long* key       = (unsigned long long*)(ws + 8184); // init
  unsigned int*       rowmin_u  = (unsigned int*)(ws + 8192);       // 64 KiB
  float*              t2arr     = (float*)(ws + 73728);             // 64 KiB
  int*                origrow   = (int*)(ws + 139264);              // 64 KiB
  float*              c2        = (float*)(ws + 204800);            // 32 KiB
  unsigned int*       cnrm      = (unsigned int*)(ws + 237568);     // 32 KiB
  unsigned short*     cbf32     = (unsigned short*)(ws + 270336);   // 512 KiB
  int*                candlist  = (int*)(ws + 270336);              // aliases cbf32 (dead by gate)
  unsigned short*     tbf32     = (unsigned short*)(ws + 794624);   // 1 MiB
  float*              tgtm      = (float*)(ws + 794624);            // aliases tbf32 (dead after phase1)

  init_kernel<<<1, 64, 0, stream>>>(ctrs, key);
  project_kernel<<<1024, 256, 0, stream>>>(x, mask, W, cbk, c2, cnrm, cbf32,
                                           tbf32, t2arr, origrow, slotctr);
  phase1_kernel<<<256, 512, 0, stream>>>(tbf32, cbf32, cnrm, t2arr, rowmin_u);
  gate_kernel<<<1, 1024, 0, stream>>>(rowmin_u, t2arr, c2, candcount, candlist);
  cproj_kernel<<<512, 256, 0, stream>>>(x, W, origrow, candcount, candlist, tgtm);
  rescore_kernel<<<512, 256, 0, stream>>>(cbk, c2, tgtm, t2arr, origrow, mask,
                                          candcount, candlist, key, resctr, out);
}